// Round 1
// baseline (277.028 us; speedup 1.0000x reference)
//
#include <hip/hip_runtime.h>
#include <cstdint>
#include <cstddef>

typedef __bf16 bf16x8 __attribute__((ext_vector_type(8)));
typedef float f32x4 __attribute__((ext_vector_type(4)));
typedef unsigned short u16;
typedef unsigned int u32;

#define S_LEN 4096
#define NH 8
#define DH 64
#define D_EMB 512
#define BATCH 2
#define M_ROWS 8192   // BATCH * S_LEN
#define GK 512        // K dim of both GEMMs

__device__ __forceinline__ u16 f2bf(float f) {
  u32 u = __builtin_bit_cast(u32, f);
  u += 0x7FFFu + ((u >> 16) & 1u);   // round-to-nearest-even
  return (u16)(u >> 16);
}
__device__ __forceinline__ float bf2f(u16 v) {
  return __builtin_bit_cast(float, (u32)v << 16);
}

#define GLD_LDS16(gsrc, ldst)                                                        \
  __builtin_amdgcn_global_load_lds(                                                  \
      (const __attribute__((address_space(1))) void*)(gsrc),                         \
      (__attribute__((address_space(3))) void*)(ldst), 16, 0, 0)

// ---------------------------------------------------------------------------
// Kernel 0: detect whether d_in buffers are bf16 (flag=0) or fp32 (flag=1).
// If underlying data is fp32, the even u16 halves are low mantissa bits with
// uniform-random "exponent" fields; if bf16, nearly all sampled exponents are
// in the N(0,1) range. Deterministic for fixed inputs.
// ---------------------------------------------------------------------------
__global__ void detect_kernel(const u16* __restrict__ x, int* __restrict__ flag) {
  __shared__ int cnt;
  if (threadIdx.x == 0) cnt = 0;
  __syncthreads();
  int plaus = 0;
  for (int i = threadIdx.x; i < 2048; i += 256) {
    u16 u = x[2 * i];
    int ex = (u >> 7) & 0xFF;
    plaus += (ex >= 100 && ex <= 134) ? 1 : 0;
  }
  atomicAdd(&cnt, plaus);
  __syncthreads();
  if (threadIdx.x == 0) *flag = (cnt > 1024) ? 0 : 1;
}

// ---------------------------------------------------------------------------
// Kernel 1: pack inputs to bf16 (x, weights) / fp32 (biases) in workspace.
// ---------------------------------------------------------------------------
__global__ void prep_kernel(const void* __restrict__ x, const void* __restrict__ wq,
                            const void* __restrict__ bq, const void* __restrict__ wo,
                            const void* __restrict__ bo,
                            u16* __restrict__ xb, u16* __restrict__ wqb,
                            u16* __restrict__ wob, float* __restrict__ bqf,
                            float* __restrict__ bof, const int* __restrict__ flag) {
  const bool f32 = (*flag != 0);
  const size_t i = (size_t)blockIdx.x * blockDim.x + threadIdx.x;
  if (i < (size_t)M_ROWS * D_EMB)
    xb[i] = f32 ? f2bf(((const float*)x)[i]) : ((const u16*)x)[i];
  if (i < (size_t)3 * D_EMB * D_EMB)
    wqb[i] = f32 ? f2bf(((const float*)wq)[i]) : ((const u16*)wq)[i];
  if (i < (size_t)D_EMB * D_EMB)
    wob[i] = f32 ? f2bf(((const float*)wo)[i]) : ((const u16*)wo)[i];
  if (i < 3 * D_EMB)
    bqf[i] = f32 ? ((const float*)bq)[i] : bf2f(((const u16*)bq)[i]);
  if (i < D_EMB)
    bof[i] = f32 ? ((const float*)bo)[i] : bf2f(((const u16*)bo)[i]);
}

// ---------------------------------------------------------------------------
// GEMM (NT): C[m,n] = sum_k A[m,k]*B[n,k] + bias[n].  A:[8192,512] B:[N,512]
// 128x128 tile, BK=64, 4 waves, global_load_lds staging, T2 XOR swizzle
// (pre-swizzled global source, swizzled LDS reads).
// EPI 0: scatter qkv -> q[B,H,S,dh] (x0.125), k[B,H,S,dh], vT[B,H,dh,S]
// EPI 1: write out-proj result to d_out (bf16 or fp32 per flag)
// ---------------------------------------------------------------------------
template <int EPI>
__global__ __launch_bounds__(256, 2)
void gemm_bt(const u16* __restrict__ A, const u16* __restrict__ B, int N,
             const float* __restrict__ bias, u16* __restrict__ qout,
             u16* __restrict__ kout, u16* __restrict__ vout, u16* __restrict__ obf,
             float* __restrict__ of32, const int* __restrict__ flag) {
  __shared__ u16 As[128 * 64];
  __shared__ u16 Bs[128 * 64];
  const int tid = threadIdx.x;
  const int wave = tid >> 6, lane = tid & 63;
  const int m0 = blockIdx.x * 128;
  const int n0 = blockIdx.y * 128;
  const int wr = (wave >> 1) * 64, wc = (wave & 1) * 64;

  // staging: lane -> dest row/col within a 32-row group
  const int sr = wave * 8 + (lane >> 3);
  const int scb = (lane & 7) * 16;  // dest col byte

  f32x4 acc[4][4] = {};

  for (int k0 = 0; k0 < GK; k0 += 64) {
#pragma unroll
    for (int i = 0; i < 4; ++i) {
      const int r = i * 32 + sr;
      const int sc = (scb ^ ((r & 7) << 4)) >> 1;  // pre-swizzled source col (elems)
      GLD_LDS16(A + (size_t)(m0 + r) * GK + k0 + sc, As + i * 2048 + wave * 512);
    }
#pragma unroll
    for (int i = 0; i < 4; ++i) {
      const int r = i * 32 + sr;
      const int sc = (scb ^ ((r & 7) << 4)) >> 1;
      GLD_LDS16(B + (size_t)(n0 + r) * GK + k0 + sc, Bs + i * 2048 + wave * 512);
    }
    __syncthreads();
#pragma unroll
    for (int kk = 0; kk < 2; ++kk) {
      const int cb = kk * 64 + ((lane >> 4) << 4);
      bf16x8 a[4], b[4];
#pragma unroll
      for (int m = 0; m < 4; ++m) {
        const int r = wr + m * 16 + (lane & 15);
        a[m] = *(const bf16x8*)((const char*)As + r * 128 + (cb ^ ((r & 7) << 4)));
      }
#pragma unroll
      for (int n = 0; n < 4; ++n) {
        const int r = wc + n * 16 + (lane & 15);
        b[n] = *(const bf16x8*)((const char*)Bs + r * 128 + (cb ^ ((r & 7) << 4)));
      }
#pragma unroll
      for (int m = 0; m < 4; ++m)
#pragma unroll
        for (int n = 0; n < 4; ++n)
          acc[m][n] = __builtin_amdgcn_mfma_f32_16x16x32_bf16(a[m], b[n], acc[m][n], 0, 0, 0);
    }
    __syncthreads();
  }

  const bool f32out = (EPI == 1) && (*flag != 0);
#pragma unroll
  for (int n = 0; n < 4; ++n) {
    const int col = n0 + wc + n * 16 + (lane & 15);
    const float bv = bias[col];
#pragma unroll
    for (int m = 0; m < 4; ++m) {
#pragma unroll
      for (int r = 0; r < 4; ++r) {
        const int row = m0 + wr + m * 16 + ((lane >> 4) << 2) + r;
        float v = acc[m][n][r] + bv;
        if (EPI == 0) {
          const int b = row >> 12, s = row & 4095;
          const int which = col >> 9, hc = col & 511;
          const int h = hc >> 6, d = hc & 63;
          const size_t bh = (size_t)(b * NH + h);
          if (which == 0) {
            qout[(bh * S_LEN + s) * DH + d] = f2bf(v * 0.125f);  // fold 1/sqrt(dh)
          } else if (which == 1) {
            kout[(bh * S_LEN + s) * DH + d] = f2bf(v);
          } else {
            vout[(bh * DH + d) * S_LEN + s] = f2bf(v);  // V transposed
          }
        } else {
          if (f32out)
            of32[(size_t)row * D_EMB + col] = v;
          else
            obf[(size_t)row * D_EMB + col] = f2bf(v);
        }
      }
    }
  }
}

// ---------------------------------------------------------------------------
// Flash attention: grid (S/64, H, B), 256 thr = 4 waves, 16 q-rows/wave.
// K staged [64kv][64d] (swizzled), V staged from vT as [64d][64kv] (swizzled),
// P via wave-private swizzled LDS. Online softmax with 16-lane shuffles.
// ---------------------------------------------------------------------------
__global__ __launch_bounds__(256, 2)
void flash_attn(const u16* __restrict__ q, const u16* __restrict__ k,
                const u16* __restrict__ vt, u16* __restrict__ ao) {
  __shared__ u16 Ks[64 * 64];
  __shared__ u16 Vs[64 * 64];
  __shared__ u16 Ps[4 * 16 * 64];
  const int tid = threadIdx.x;
  const int wave = tid >> 6, lane = tid & 63;
  const int s0 = blockIdx.x * 64;
  const int h = blockIdx.y, b = blockIdx.z;
  const size_t bh = (size_t)(b * NH + h);
  const u16* qp = q + bh * S_LEN * DH;
  const u16* kp = k + bh * S_LEN * DH;
  const u16* vp = vt + bh * DH * S_LEN;

  // Q fragments (held in registers for the whole KV loop)
  bf16x8 qf[2];
  {
    const int r = s0 + wave * 16 + (lane & 15);
    const char* base = (const char*)(qp + (size_t)r * DH);
    qf[0] = *(const bf16x8*)(base + ((lane >> 4) << 4));
    qf[1] = *(const bf16x8*)(base + 64 + ((lane >> 4) << 4));
  }

  f32x4 oacc[4] = {};
  float mstate[4], lstate[4];
#pragma unroll
  for (int r = 0; r < 4; ++r) { mstate[r] = -1e30f; lstate[r] = 0.f; }

  const int sr = wave * 8 + (lane >> 3);
  const int scb = (lane & 7) * 16;

  for (int kv = 0; kv < S_LEN; kv += 64) {
    // stage K tile [64][64] and V^T tile [64][64] (pre-swizzled source)
#pragma unroll
    for (int i = 0; i < 2; ++i) {
      const int r = i * 32 + sr;
      const int sc = (scb ^ ((r & 7) << 4)) >> 1;
      GLD_LDS16(kp + (size_t)(kv + r) * DH + sc, Ks + i * 2048 + wave * 512);
      GLD_LDS16(vp + (size_t)r * S_LEN + kv + sc, Vs + i * 2048 + wave * 512);
    }
    __syncthreads();

    // QK^T: s[n] covers kk-cols [n*16, n*16+16)
    f32x4 s[4] = {};
#pragma unroll
    for (int kk = 0; kk < 2; ++kk) {
      const int cb = kk * 64 + ((lane >> 4) << 4);
#pragma unroll
      for (int n = 0; n < 4; ++n) {
        const int r = n * 16 + (lane & 15);
        bf16x8 kf = *(const bf16x8*)((const char*)Ks + r * 128 + (cb ^ ((r & 7) << 4)));
        s[n] = __builtin_amdgcn_mfma_f32_16x16x32_bf16(qf[kk], kf, s[n], 0, 0, 0);
      }
    }

    // online softmax; lane holds rows (lane>>4)*4+r, col n*16+(lane&15)
    float alpha[4];
#pragma unroll
    for (int r = 0; r < 4; ++r) {
      float mx = fmaxf(fmaxf(s[0][r], s[1][r]), fmaxf(s[2][r], s[3][r]));
#pragma unroll
      for (int off = 8; off; off >>= 1) mx = fmaxf(mx, __shfl_xor(mx, off, 16));
      const float Mn = fmaxf(mstate[r], mx);
      alpha[r] = __expf(mstate[r] - Mn);
      mstate[r] = Mn;
      float rs = 0.f;
#pragma unroll
      for (int n = 0; n < 4; ++n) {
        const float p = __expf(s[n][r] - Mn);
        s[n][r] = p;
        rs += p;
      }
#pragma unroll
      for (int off = 8; off; off >>= 1) rs += __shfl_xor(rs, off, 16);
      lstate[r] = lstate[r] * alpha[r] + rs;
#pragma unroll
      for (int n = 0; n < 4; ++n) oacc[n][r] *= alpha[r];
    }

    // P -> wave-private LDS (bf16, swizzled)
    char* pbase = (char*)Ps + wave * 2048;
#pragma unroll
    for (int n = 0; n < 4; ++n) {
#pragma unroll
      for (int r = 0; r < 4; ++r) {
        const int rr = ((lane >> 4) << 2) + r;
        const int cb = (n * 16 + (lane & 15)) * 2;
        *(u16*)(pbase + rr * 128 + (cb ^ ((rr & 7) << 4))) = f2bf(s[n][r]);
      }
    }

    // PV: oacc[n] += P[16x64] * V[64 x 16d(n)]
#pragma unroll
    for (int kk = 0; kk < 2; ++kk) {
      const int cb = kk * 64 + ((lane >> 4) << 4);
      const int pr = lane & 15;
      bf16x8 pf = *(const bf16x8*)(pbase + pr * 128 + (cb ^ ((pr & 7) << 4)));
#pragma unroll
      for (int n = 0; n < 4; ++n) {
        const int vr = n * 16 + (lane & 15);
        bf16x8 vf = *(const bf16x8*)((const char*)Vs + vr * 128 + (cb ^ ((vr & 7) << 4)));
        oacc[n] = __builtin_amdgcn_mfma_f32_16x16x32_bf16(pf, vf, oacc[n], 0, 0, 0);
      }
    }
    __syncthreads();
  }

  // epilogue: normalize and write attn output in [B,S,512] layout
#pragma unroll
  for (int n = 0; n < 4; ++n) {
#pragma unroll
    for (int r = 0; r < 4; ++r) {
      const int row = s0 + wave * 16 + ((lane >> 4) << 2) + r;
      const int d = h * DH + n * 16 + (lane & 15);
      const float v = oacc[n][r] / lstate[r];
      ao[(size_t)(b * S_LEN + row) * D_EMB + d] = f2bf(v);
    }
  }
}

// ---------------------------------------------------------------------------
extern "C" void kernel_launch(void* const* d_in, const int* in_sizes, int n_in,
                              void* d_out, int out_size, void* d_ws, size_t ws_size,
                              hipStream_t stream) {
  char* w = (char*)d_ws;
  int* flag = (int*)w;
  u16* xb = (u16*)(w + 256);                    // 8,388,608 B
  u16* wqb = (u16*)(w + 8388864);               // 1,572,864 B
  u16* wob = (u16*)(w + 9961728);               //   524,288 B
  float* bqf = (float*)(w + 10486016);          //     6,144 B
  float* bof = (float*)(w + 10492160);          //     2,048 B
  u16* qq = (u16*)(w + 10494208);               // 8,388,608 B
  u16* kk = (u16*)(w + 18882816);               // 8,388,608 B
  u16* vt = (u16*)(w + 27271424);               // 8,388,608 B
  u16* ao = (u16*)(w + 35660032);               // 8,388,608 B  (end 44,048,640)

  detect_kernel<<<1, 256, 0, stream>>>((const u16*)d_in[0], flag);
  prep_kernel<<<16384, 256, 0, stream>>>(d_in[0], d_in[1], d_in[2], d_in[3], d_in[4],
                                         xb, wqb, wob, bqf, bof, flag);
  gemm_bt<0><<<dim3(64, 12), 256, 0, stream>>>(xb, wqb, 3 * D_EMB, bqf, qq, kk, vt,
                                               nullptr, nullptr, flag);
  flash_attn<<<dim3(64, NH, BATCH), 256, 0, stream>>>(qq, kk, vt, ao);
  gemm_bt<1><<<dim3(64, 4), 256, 0, stream>>>(ao, wob, D_EMB, bof, nullptr, nullptr,
                                              nullptr, (u16*)d_out, (float*)d_out, flag);
}

// Round 2
// 255.240 us; speedup vs baseline: 1.0854x; 1.0854x over previous
//
#include <hip/hip_runtime.h>
#include <cstdint>
#include <cstddef>

typedef __bf16 bf16x8 __attribute__((ext_vector_type(8)));
typedef float f32x4 __attribute__((ext_vector_type(4)));
typedef unsigned short u16;
typedef unsigned int u32;

#define S_LEN 4096
#define NH 8
#define DH 64
#define D_EMB 512
#define BATCH 2
#define M_ROWS 8192   // BATCH * S_LEN
#define GK 512        // K dim of both GEMMs

__device__ __forceinline__ u16 f2bf(float f) {
  u32 u = __builtin_bit_cast(u32, f);
  u += 0x7FFFu + ((u >> 16) & 1u);   // round-to-nearest-even
  return (u16)(u >> 16);
}
__device__ __forceinline__ float bf2f(u16 v) {
  return __builtin_bit_cast(float, (u32)v << 16);
}

#define GLD_LDS16(gsrc, ldst)                                                        \
  __builtin_amdgcn_global_load_lds(                                                  \
      (const __attribute__((address_space(1))) void*)(gsrc),                         \
      (__attribute__((address_space(3))) void*)(ldst), 16, 0, 0)

// ---------------------------------------------------------------------------
// Kernel 0: detect whether d_in buffers are bf16 (flag=0) or fp32 (flag=1).
// ---------------------------------------------------------------------------
__global__ void detect_kernel(const u16* __restrict__ x, int* __restrict__ flag) {
  __shared__ int cnt;
  if (threadIdx.x == 0) cnt = 0;
  __syncthreads();
  int plaus = 0;
  for (int i = threadIdx.x; i < 2048; i += 256) {
    u16 u = x[2 * i];
    int ex = (u >> 7) & 0xFF;
    plaus += (ex >= 100 && ex <= 134) ? 1 : 0;
  }
  atomicAdd(&cnt, plaus);
  __syncthreads();
  if (threadIdx.x == 0) *flag = (cnt > 1024) ? 0 : 1;
}

// ---------------------------------------------------------------------------
// Kernel 1: pack inputs to bf16 (x, weights) / fp32 (biases) in workspace.
// ---------------------------------------------------------------------------
__global__ void prep_kernel(const void* __restrict__ x, const void* __restrict__ wq,
                            const void* __restrict__ bq, const void* __restrict__ wo,
                            const void* __restrict__ bo,
                            u16* __restrict__ xb, u16* __restrict__ wqb,
                            u16* __restrict__ wob, float* __restrict__ bqf,
                            float* __restrict__ bof, const int* __restrict__ flag) {
  const bool f32 = (*flag != 0);
  const size_t i = (size_t)blockIdx.x * blockDim.x + threadIdx.x;
  if (i < (size_t)M_ROWS * D_EMB)
    xb[i] = f32 ? f2bf(((const float*)x)[i]) : ((const u16*)x)[i];
  if (i < (size_t)3 * D_EMB * D_EMB)
    wqb[i] = f32 ? f2bf(((const float*)wq)[i]) : ((const u16*)wq)[i];
  if (i < (size_t)D_EMB * D_EMB)
    wob[i] = f32 ? f2bf(((const float*)wo)[i]) : ((const u16*)wo)[i];
  if (i < 3 * D_EMB)
    bqf[i] = f32 ? ((const float*)bq)[i] : bf2f(((const u16*)bq)[i]);
  if (i < D_EMB)
    bof[i] = f32 ? ((const float*)bo)[i] : bf2f(((const u16*)bo)[i]);
}

// ---------------------------------------------------------------------------
// GEMM (NT): C[m,n] = sum_k A[m,k]*B[n,k] + bias[n].  (unchanged this round)
// ---------------------------------------------------------------------------
template <int EPI>
__global__ __launch_bounds__(256, 2)
void gemm_bt(const u16* __restrict__ A, const u16* __restrict__ B, int N,
             const float* __restrict__ bias, u16* __restrict__ qout,
             u16* __restrict__ kout, u16* __restrict__ vout, u16* __restrict__ obf,
             float* __restrict__ of32, const int* __restrict__ flag) {
  __shared__ u16 As[128 * 64];
  __shared__ u16 Bs[128 * 64];
  const int tid = threadIdx.x;
  const int wave = tid >> 6, lane = tid & 63;
  const int m0 = blockIdx.x * 128;
  const int n0 = blockIdx.y * 128;
  const int wr = (wave >> 1) * 64, wc = (wave & 1) * 64;

  const int sr = wave * 8 + (lane >> 3);
  const int scb = (lane & 7) * 16;

  f32x4 acc[4][4] = {};

  for (int k0 = 0; k0 < GK; k0 += 64) {
#pragma unroll
    for (int i = 0; i < 4; ++i) {
      const int r = i * 32 + sr;
      const int sc = (scb ^ ((r & 7) << 4)) >> 1;
      GLD_LDS16(A + (size_t)(m0 + r) * GK + k0 + sc, As + i * 2048 + wave * 512);
    }
#pragma unroll
    for (int i = 0; i < 4; ++i) {
      const int r = i * 32 + sr;
      const int sc = (scb ^ ((r & 7) << 4)) >> 1;
      GLD_LDS16(B + (size_t)(n0 + r) * GK + k0 + sc, Bs + i * 2048 + wave * 512);
    }
    __syncthreads();
#pragma unroll
    for (int kk = 0; kk < 2; ++kk) {
      const int cb = kk * 64 + ((lane >> 4) << 4);
      bf16x8 a[4], b[4];
#pragma unroll
      for (int m = 0; m < 4; ++m) {
        const int r = wr + m * 16 + (lane & 15);
        a[m] = *(const bf16x8*)((const char*)As + r * 128 + (cb ^ ((r & 7) << 4)));
      }
#pragma unroll
      for (int n = 0; n < 4; ++n) {
        const int r = wc + n * 16 + (lane & 15);
        b[n] = *(const bf16x8*)((const char*)Bs + r * 128 + (cb ^ ((r & 7) << 4)));
      }
#pragma unroll
      for (int m = 0; m < 4; ++m)
#pragma unroll
        for (int n = 0; n < 4; ++n)
          acc[m][n] = __builtin_amdgcn_mfma_f32_16x16x32_bf16(a[m], b[n], acc[m][n], 0, 0, 0);
    }
    __syncthreads();
  }

  const bool f32out = (EPI == 1) && (*flag != 0);
#pragma unroll
  for (int n = 0; n < 4; ++n) {
    const int col = n0 + wc + n * 16 + (lane & 15);
    const float bv = bias[col];
#pragma unroll
    for (int m = 0; m < 4; ++m) {
#pragma unroll
      for (int r = 0; r < 4; ++r) {
        const int row = m0 + wr + m * 16 + ((lane >> 4) << 2) + r;
        float v = acc[m][n][r] + bv;
        if (EPI == 0) {
          const int b = row >> 12, s = row & 4095;
          const int which = col >> 9, hc = col & 511;
          const int h = hc >> 6, d = hc & 63;
          const size_t bh = (size_t)(b * NH + h);
          if (which == 0) {
            qout[(bh * S_LEN + s) * DH + d] = f2bf(v * 0.125f);
          } else if (which == 1) {
            kout[(bh * S_LEN + s) * DH + d] = f2bf(v);
          } else {
            vout[(bh * DH + d) * S_LEN + s] = f2bf(v);
          }
        } else {
          if (f32out)
            of32[(size_t)row * D_EMB + col] = v;
          else
            obf[(size_t)row * D_EMB + col] = f2bf(v);
        }
      }
    }
  }
}

// ---------------------------------------------------------------------------
// Flash attention, round 2: double-buffered K/V staging with raw s_barrier +
// counted vmcnt (T3 2-phase + T4), occupancy 4 blocks/CU.
// grid (S/64, H, B), 256 thr = 4 waves, 16 q-rows/wave, KVBLK=64.
// ---------------------------------------------------------------------------
__global__ __launch_bounds__(256, 4)
void flash_attn(const u16* __restrict__ q, const u16* __restrict__ k,
                const u16* __restrict__ vt, u16* __restrict__ ao) {
  __shared__ u16 Ks[2][64 * 64];
  __shared__ u16 Vs[2][64 * 64];
  __shared__ u16 Ps[4 * 16 * 64];
  const int tid = threadIdx.x;
  const int wave = tid >> 6, lane = tid & 63;
  const int s0 = blockIdx.x * 64;
  const int h = blockIdx.y, b = blockIdx.z;
  const size_t bh = (size_t)(b * NH + h);
  const u16* qp = q + bh * S_LEN * DH;
  const u16* kp = k + bh * S_LEN * DH;
  const u16* vp = vt + bh * DH * S_LEN;

  // Q fragments (registers for whole KV loop)
  bf16x8 qf[2];
  {
    const int r = s0 + wave * 16 + (lane & 15);
    const char* base = (const char*)(qp + (size_t)r * DH);
    qf[0] = *(const bf16x8*)(base + ((lane >> 4) << 4));
    qf[1] = *(const bf16x8*)(base + 64 + ((lane >> 4) << 4));
  }

  f32x4 oacc[4] = {};
  float mstate[4], lstate[4];
#pragma unroll
  for (int r = 0; r < 4; ++r) { mstate[r] = -1e30f; lstate[r] = 0.f; }

  const int sr = wave * 8 + (lane >> 3);
  const int scb = (lane & 7) * 16;
  const int sc = (scb ^ ((sr & 7) << 4)) >> 1;  // (i*32+sr)&7 == sr&7

  // stage one 64-kv tile (4 global_load_lds per wave) into buffer `bi`
#define STAGE(bi, kvoff)                                                              \
  do {                                                                                \
    GLD_LDS16(kp + (size_t)((kvoff) + sr) * DH + sc, Ks[bi] + wave * 512);            \
    GLD_LDS16(kp + (size_t)((kvoff) + 32 + sr) * DH + sc, Ks[bi] + 2048 + wave * 512);\
    GLD_LDS16(vp + (size_t)sr * S_LEN + (kvoff) + sc, Vs[bi] + wave * 512);           \
    GLD_LDS16(vp + (size_t)(32 + sr) * S_LEN + (kvoff) + sc, Vs[bi] + 2048 + wave * 512);\
  } while (0)

  STAGE(0, 0);

#pragma unroll 1
  for (int t = 0; t < S_LEN / 64; ++t) {
    const int cur = t & 1;
    if (t + 1 < S_LEN / 64) {
      STAGE(cur ^ 1, (t + 1) * 64);               // next tile in flight across barrier
      asm volatile("s_waitcnt vmcnt(4)" ::: "memory");  // current tile landed
    } else {
      asm volatile("s_waitcnt vmcnt(0)" ::: "memory");
    }
    __builtin_amdgcn_s_barrier();
    __builtin_amdgcn_sched_barrier(0);

    const u16* ksb = Ks[cur];
    const u16* vsb = Vs[cur];

    // QK^T
    f32x4 s[4] = {};
#pragma unroll
    for (int kk = 0; kk < 2; ++kk) {
      const int cb = kk * 64 + ((lane >> 4) << 4);
#pragma unroll
      for (int n = 0; n < 4; ++n) {
        const int r = n * 16 + (lane & 15);
        bf16x8 kf = *(const bf16x8*)((const char*)ksb + r * 128 + (cb ^ ((r & 7) << 4)));
        s[n] = __builtin_amdgcn_mfma_f32_16x16x32_bf16(qf[kk], kf, s[n], 0, 0, 0);
      }
    }

    // online softmax
    float alpha[4];
#pragma unroll
    for (int r = 0; r < 4; ++r) {
      float mx = fmaxf(fmaxf(s[0][r], s[1][r]), fmaxf(s[2][r], s[3][r]));
#pragma unroll
      for (int off = 8; off; off >>= 1) mx = fmaxf(mx, __shfl_xor(mx, off, 16));
      const float Mn = fmaxf(mstate[r], mx);
      alpha[r] = __expf(mstate[r] - Mn);
      mstate[r] = Mn;
      float rs = 0.f;
#pragma unroll
      for (int n = 0; n < 4; ++n) {
        const float p = __expf(s[n][r] - Mn);
        s[n][r] = p;
        rs += p;
      }
#pragma unroll
      for (int off = 8; off; off >>= 1) rs += __shfl_xor(rs, off, 16);
      lstate[r] = lstate[r] * alpha[r] + rs;
#pragma unroll
      for (int n = 0; n < 4; ++n) oacc[n][r] *= alpha[r];
    }

    // P -> wave-private LDS (bf16, swizzled)
    char* pbase = (char*)Ps + wave * 2048;
#pragma unroll
    for (int n = 0; n < 4; ++n) {
#pragma unroll
      for (int r = 0; r < 4; ++r) {
        const int rr = ((lane >> 4) << 2) + r;
        const int cb = (n * 16 + (lane & 15)) * 2;
        *(u16*)(pbase + rr * 128 + (cb ^ ((rr & 7) << 4))) = f2bf(s[n][r]);
      }
    }

    // PV
#pragma unroll
    for (int kk = 0; kk < 2; ++kk) {
      const int cb = kk * 64 + ((lane >> 4) << 4);
      const int pr = lane & 15;
      bf16x8 pf = *(const bf16x8*)(pbase + pr * 128 + (cb ^ ((pr & 7) << 4)));
#pragma unroll
      for (int n = 0; n < 4; ++n) {
        const int vr = n * 16 + (lane & 15);
        bf16x8 vf = *(const bf16x8*)((const char*)vsb + vr * 128 + (cb ^ ((vr & 7) << 4)));
        oacc[n] = __builtin_amdgcn_mfma_f32_16x16x32_bf16(pf, vf, oacc[n], 0, 0, 0);
      }
    }

    __builtin_amdgcn_sched_barrier(0);
    __builtin_amdgcn_s_barrier();
  }
#undef STAGE

  // epilogue: normalize and write attn output in [B,S,512] layout
#pragma unroll
  for (int r = 0; r < 4; ++r) {
    const float rinv = 1.f / lstate[r];
    const int row = s0 + wave * 16 + ((lane >> 4) << 2) + r;
#pragma unroll
    for (int n = 0; n < 4; ++n) {
      const int d = h * DH + n * 16 + (lane & 15);
      ao[(size_t)(b * S_LEN + row) * D_EMB + d] = f2bf(oacc[n][r] * rinv);
    }
  }
}

// ---------------------------------------------------------------------------
extern "C" void kernel_launch(void* const* d_in, const int* in_sizes, int n_in,
                              void* d_out, int out_size, void* d_ws, size_t ws_size,
                              hipStream_t stream) {
  char* w = (char*)d_ws;
  int* flag = (int*)w;
  u16* xb = (u16*)(w + 256);
  u16* wqb = (u16*)(w + 8388864);
  u16* wob = (u16*)(w + 9961728);
  float* bqf = (float*)(w + 10486016);
  float* bof = (float*)(w + 10492160);
  u16* qq = (u16*)(w + 10494208);
  u16* kk = (u16*)(w + 18882816);
  u16* vt = (u16*)(w + 27271424);
  u16* ao = (u16*)(w + 35660032);

  detect_kernel<<<1, 256, 0, stream>>>((const u16*)d_in[0], flag);
  prep_kernel<<<16384, 256, 0, stream>>>(d_in[0], d_in[1], d_in[2], d_in[3], d_in[4],
                                         xb, wqb, wob, bqf, bof, flag);
  gemm_bt<0><<<dim3(64, 12), 256, 0, stream>>>(xb, wqb, 3 * D_EMB, bqf, qq, kk, vt,
                                               nullptr, nullptr, flag);
  flash_attn<<<dim3(64, NH, BATCH), 256, 0, stream>>>(qq, kk, vt, ao);
  gemm_bt<1><<<dim3(64, 4), 256, 0, stream>>>(ao, wob, D_EMB, bof, nullptr, nullptr,
                                              nullptr, (u16*)d_out, (float*)d_out, flag);
}